// Round 1
// baseline (632.149 us; speedup 1.0000x reference)
//
#include <hip/hip_runtime.h>

typedef unsigned int u32;
typedef unsigned short u16;
typedef short bf16x8 __attribute__((ext_vector_type(8)));
typedef float f32x4 __attribute__((ext_vector_type(4)));

#define KOFF 27

__device__ __forceinline__ float bf2f(u16 u) {
    u32 x = ((u32)u) << 16;
    return __builtin_bit_cast(float, x);
}
__device__ __forceinline__ u16 f2bf(float f) {
    u32 u = __builtin_bit_cast(u32, f);
    u32 r = (u + 0x7FFFu + ((u >> 16) & 1u)) >> 16;  // RNE
    return (u16)r;
}
__device__ __forceinline__ void async16(void* lds, const void* g) {
    __builtin_amdgcn_global_load_lds(
        (const __attribute__((address_space(1))) u32*)g,
        (__attribute__((address_space(3))) u32*)lds, 16, 0, 0);
}

// ---------------------------------------------------------------------------
// Weight prep: W[k][c][d] fp32 -> bf16 Wt[k][d][c ^ ((d&7)<<3)]  (transpose +
// XOR swizzle baked in so conv's B-tile stages linearly via global_load_lds).
// One launch per weight; grid = 27 k * 2 d-halves = 54 blocks.
// ---------------------------------------------------------------------------
__global__ __launch_bounds__(256) void prep_w(const float* __restrict__ src,
                                              u16* __restrict__ dst) {
    __shared__ float t[128][65];  // [c][dl], padded
    const int k = blockIdx.x >> 1, half = blockIdx.x & 1;
    const float* s = src + k * 16384 + half * 64;
    for (int i = threadIdx.x; i < 8192; i += 256) {
        int c = i >> 6, dl = i & 63;
        t[c][dl] = s[c * 128 + dl];
    }
    __syncthreads();
    u16* db = dst + k * 16384;
    for (int i = threadIdx.x; i < 8192; i += 256) {
        int dl = i >> 7, c = i & 127;
        int d = half * 64 + dl;
        int c_sw = c ^ ((d & 7) << 3);
        db[d * 128 + c_sw] = f2bf(t[c][dl]);
    }
}

// f0[n][c] = prior_emb[x_O[n]][c]  (fp32 -> bf16)
__global__ __launch_bounds__(256) void embed_k(const int* __restrict__ xO,
                                               const float* __restrict__ emb,
                                               u16* __restrict__ out) {
    int idx = blockIdx.x * 256 + threadIdx.x;
    int c = idx & 127, n = idx >> 7;
    out[idx] = f2bf(emb[xO[n] * 128 + c]);
}

// g[m][c] = f[m>>3][c] + oct_emb[child_oct[m]][c]
__global__ __launch_bounds__(256) void expand_k(const u16* __restrict__ f,
                                                const int* __restrict__ oct,
                                                const float* __restrict__ oemb,
                                                u16* __restrict__ g) {
    int idx = blockIdx.x * 256 + threadIdx.x;
    int c = idx & 127, m = idx >> 7;
    g[idx] = f2bf(bf2f(f[(m >> 3) * 128 + c]) + oemb[oct[m] * 128 + c]);
}

// ---------------------------------------------------------------------------
// Sparse conv: out[p][d] = relu( sum_k sum_c in[nbr[p][k]][c] * W[k][c][d]
//                                (+ res[p][d]) )
// BM points/block, 4 waves, mfma 16x16x32 bf16.  A gathered via per-lane
// global_load_lds source, B staged linearly from pre-swizzled Wt.
// LDS: A = BM*256 B, B = 32 KB.  Swizzle: byte-in-row ^= (row&7)<<4.
// ---------------------------------------------------------------------------
template <int BM>
__global__ __launch_bounds__(256, 2) void conv_kernel(
    const u16* __restrict__ fin, const int* __restrict__ nbr,
    const u16* __restrict__ wt, const u16* __restrict__ res,
    u16* __restrict__ fout) {
    constexpr int MR = BM / 32;
    __shared__ __align__(16) u16 Asb[BM * 128];
    __shared__ __align__(16) u16 Bsb[128 * 128];
    const int tid = threadIdx.x;
    const int wid = tid >> 6;
    const int lane = tid & 63;
    const int p0 = blockIdx.x * BM;

    f32x4 acc[MR][4];
#pragma unroll
    for (int m = 0; m < MR; ++m)
#pragma unroll
        for (int n = 0; n < 4; ++n) acc[m][n] = f32x4{0.f, 0.f, 0.f, 0.f};

    const int RB = (wid >> 1) * (BM / 2);  // wave row base
    const int CB = (wid & 1) * 64;         // wave col base
    const int lrow = lane & 15;
    const int lkb = (lane >> 4) * 16;      // k-chunk byte offset within 64B

#pragma unroll 1
    for (int k = 0; k < KOFF; ++k) {
        // stage A (gathered rows, swizzled source)
#pragma unroll
        for (int i = 0; i < BM / 16; ++i) {
            int o = i * 4096 + tid * 16;
            int r = o >> 8;
            int cbs = (o & 255) ^ ((r & 7) << 4);
            int rg = nbr[(p0 + r) * KOFF + k];
            async16((char*)Asb + i * 4096 + wid * 1024,
                    (const char*)fin + rg * 256 + cbs);
        }
        // stage B (pre-swizzled weights, linear copy)
        const char* wk = (const char*)wt + k * 32768;
#pragma unroll
        for (int i = 0; i < 8; ++i) {
            int o = i * 4096 + tid * 16;
            async16((char*)Bsb + i * 4096 + wid * 1024, wk + o);
        }
        __syncthreads();

#pragma unroll
        for (int kk = 0; kk < 4; ++kk) {
            bf16x8 av[MR], bv[4];
#pragma unroll
            for (int m = 0; m < MR; ++m) {
                int row = RB + m * 16 + lrow;
                int cb = (kk * 64 + lkb) ^ ((row & 7) << 4);
                av[m] = *(const bf16x8*)((const char*)Asb + row * 256 + cb);
            }
#pragma unroll
            for (int n = 0; n < 4; ++n) {
                int drow = CB + n * 16 + lrow;
                int cb = (kk * 64 + lkb) ^ ((drow & 7) << 4);
                bv[n] = *(const bf16x8*)((const char*)Bsb + drow * 256 + cb);
            }
#pragma unroll
            for (int m = 0; m < MR; ++m)
#pragma unroll
                for (int n = 0; n < 4; ++n)
                    acc[m][n] = __builtin_amdgcn_mfma_f32_16x16x32_bf16(
                        av[m], bv[n], acc[m][n], 0, 0, 0);
        }
        __syncthreads();
    }

    // epilogue: (+res), relu, -> bf16.  D layout: col=lane&15, row=(lane>>4)*4+q
#pragma unroll
    for (int m = 0; m < MR; ++m) {
        int prow = p0 + RB + m * 16 + (lane >> 4) * 4;
#pragma unroll
        for (int n = 0; n < 4; ++n) {
            int dcol = CB + n * 16 + lrow;
#pragma unroll
            for (int q = 0; q < 4; ++q) {
                float v = acc[m][n][q];
                int p = prow + q;
                if (res) v += bf2f(res[p * 128 + dcol]);
                v = v > 0.f ? v : 0.f;
                fout[p * 128 + dcol] = f2bf(v);
            }
        }
    }
}

// ---------------------------------------------------------------------------
// Heads: for 8 points/block compute both 2-layer MLP heads + softmax(16) +
// gathered -log2 prob, deterministic per-block partial sum.
// ---------------------------------------------------------------------------
__global__ __launch_bounds__(128) void heads_k(
    const u16* __restrict__ g, const int* __restrict__ gtO,
    const float* __restrict__ s1emb, const float* __restrict__ W1a,
    const float* __restrict__ b1a, const float* __restrict__ W2a,
    const float* __restrict__ b2a, const float* __restrict__ W1b,
    const float* __restrict__ b1b, const float* __restrict__ W2b,
    const float* __restrict__ b2b, float* __restrict__ partial) {
    __shared__ float gl[8][128];
    __shared__ float hl[8][128];
    __shared__ int gts[2][8];
    __shared__ float bitsv[16];
    const int tid = threadIdx.x;
    const int p0 = blockIdx.x * 8;
    if (tid < 8) {
        int gt = gtO[p0 + tid];
        gts[0][tid] = gt & 15;
        gts[1][tid] = gt >> 4;
    }
    for (int i = tid; i < 1024; i += 128)
        gl[i >> 7][i & 127] = bf2f(g[p0 * 128 + i]);
    __syncthreads();

    const int pp = tid >> 4, jj = tid & 15;
#pragma unroll
    for (int stage = 0; stage < 2; ++stage) {
        const float* W1 = stage ? W1b : W1a;
        const float* b1 = stage ? b1b : b1a;
        const float* W2 = stage ? W2b : W2a;
        const float* b2 = stage ? b2b : b2a;
        if (stage) {
#pragma unroll
            for (int p = 0; p < 8; ++p)
                gl[p][tid] += s1emb[gts[0][p] * 128 + tid];
            __syncthreads();
        }
        float a[8];
#pragma unroll
        for (int p = 0; p < 8; ++p) a[p] = b1[tid];
        for (int c = 0; c < 128; ++c) {
            float w = W1[c * 128 + tid];
#pragma unroll
            for (int p = 0; p < 8; ++p) a[p] = fmaf(gl[p][c], w, a[p]);
        }
        __syncthreads();
#pragma unroll
        for (int p = 0; p < 8; ++p) hl[p][tid] = a[p] > 0.f ? a[p] : 0.f;
        __syncthreads();
        float lg = b2[jj];
        for (int d = 0; d < 128; ++d) lg = fmaf(hl[pp][d], W2[d * 16 + jj], lg);
        float mx = lg;
#pragma unroll
        for (int o = 1; o < 16; o <<= 1) mx = fmaxf(mx, __shfl_xor(mx, o, 16));
        float e = expf(lg - mx);
        float sm = e;
#pragma unroll
        for (int o = 1; o < 16; o <<= 1) sm += __shfl_xor(sm, o, 16);
        if (jj == gts[stage][pp]) {
            float b = e / sm + 1e-10f;
            float bits = -log2f(b);
            bitsv[stage * 8 + pp] = fminf(fmaxf(bits, 0.f), 50.f);
        }
        __syncthreads();
    }
    if (tid == 0) {
        float s = 0.f;
#pragma unroll
        for (int i = 0; i < 16; ++i) s += bitsv[i];
        partial[blockIdx.x] = s;
    }
}

__global__ __launch_bounds__(256) void finalize_k(const float* __restrict__ partial,
                                                  float* __restrict__ out) {
    float s = 0.f;
    for (int i = threadIdx.x; i < 4096; i += 256) s += partial[i];
#pragma unroll
    for (int o = 32; o > 0; o >>= 1) s += __shfl_down(s, o, 64);
    __shared__ float wsum[4];
    if ((threadIdx.x & 63) == 0) wsum[threadIdx.x >> 6] = s;
    __syncthreads();
    if (threadIdx.x == 0)
        out[0] = (wsum[0] + wsum[1] + wsum[2] + wsum[3]) * (1.0f / 4096.0f);
}

// ---------------------------------------------------------------------------
extern "C" void kernel_launch(void* const* d_in, const int* in_sizes, int n_in,
                              void* d_out, int out_size, void* d_ws,
                              size_t ws_size, hipStream_t stream) {
    const int N = 4096, M = 32768;
    const int* x_O = (const int*)d_in[0];
    const int* gt_O = (const int*)d_in[1];
    const int* nbr_par = (const int*)d_in[2];
    const int* nbr_ch = (const int*)d_in[3];
    const int* child_oct = (const int*)d_in[4];
    const float* prior_emb = (const float*)d_in[5];
    const float* convW[10] = {
        (const float*)d_in[6],  (const float*)d_in[7],  (const float*)d_in[8],
        (const float*)d_in[9],  (const float*)d_in[10], (const float*)d_in[12],
        (const float*)d_in[13], (const float*)d_in[14], (const float*)d_in[15],
        (const float*)d_in[16]};
    const float* oct_emb = (const float*)d_in[11];
    const float* s1_emb = (const float*)d_in[17];
    const float* h0W1 = (const float*)d_in[18];
    const float* h0b1 = (const float*)d_in[19];
    const float* h0W2 = (const float*)d_in[20];
    const float* h0b2 = (const float*)d_in[21];
    const float* h1W1 = (const float*)d_in[22];
    const float* h1b1 = (const float*)d_in[23];
    const float* h1W2 = (const float*)d_in[24];
    const float* h1b2 = (const float*)d_in[25];

    // workspace layout (~37 MB)
    char* ws = (char*)d_ws;
    size_t off = 0;
    auto alloc = [&](size_t b) {
        void* p = ws + off;
        off += (b + 255) & ~(size_t)255;
        return p;
    };
    u16* wb[10];
    for (int i = 0; i < 10; ++i) wb[i] = (u16*)alloc(27 * 128 * 128 * 2);
    u16* fA = (u16*)alloc((size_t)N * 256);
    u16* fB = (u16*)alloc((size_t)N * 256);
    u16* fC = (u16*)alloc((size_t)N * 256);
    u16* gA = (u16*)alloc((size_t)M * 256);
    u16* gB = (u16*)alloc((size_t)M * 256);
    u16* gC = (u16*)alloc((size_t)M * 256);
    float* partial = (float*)alloc(4096 * 4);

    for (int i = 0; i < 10; ++i)
        prep_w<<<54, 256, 0, stream>>>(convW[i], wb[i]);
    embed_k<<<N * 128 / 256, 256, 0, stream>>>(x_O, prior_emb, fA);

    // parent stack
    conv_kernel<64><<<N / 64, 256, 0, stream>>>(fA, nbr_par, wb[0], nullptr, fB);
    conv_kernel<64><<<N / 64, 256, 0, stream>>>(fB, nbr_par, wb[1], nullptr, fC);
    conv_kernel<64><<<N / 64, 256, 0, stream>>>(fC, nbr_par, wb[2], fB, fA);
    conv_kernel<64><<<N / 64, 256, 0, stream>>>(fA, nbr_par, wb[3], nullptr, fC);
    conv_kernel<64><<<N / 64, 256, 0, stream>>>(fC, nbr_par, wb[4], fA, fB);

    // expand to children
    expand_k<<<M * 128 / 256, 256, 0, stream>>>(fB, child_oct, oct_emb, gA);

    // child stack
    conv_kernel<128><<<M / 128, 256, 0, stream>>>(gA, nbr_ch, wb[5], nullptr, gB);
    conv_kernel<128><<<M / 128, 256, 0, stream>>>(gB, nbr_ch, wb[6], nullptr, gC);
    conv_kernel<128><<<M / 128, 256, 0, stream>>>(gC, nbr_ch, wb[7], gB, gA);
    conv_kernel<128><<<M / 128, 256, 0, stream>>>(gA, nbr_ch, wb[8], nullptr, gC);
    conv_kernel<128><<<M / 128, 256, 0, stream>>>(gC, nbr_ch, wb[9], gA, gB);

    heads_k<<<M / 8, 128, 0, stream>>>(gB, gt_O, s1_emb, h0W1, h0b1, h0W2, h0b2,
                                       h1W1, h1b1, h1W2, h1b2, partial);
    finalize_k<<<1, 256, 0, stream>>>(partial, (float*)d_out);

    (void)in_sizes; (void)n_in; (void)out_size; (void)ws_size;
}

// Round 2
// 443.338 us; speedup vs baseline: 1.4259x; 1.4259x over previous
//
#include <hip/hip_runtime.h>

typedef unsigned int u32;
typedef unsigned short u16;
typedef short bf16x8 __attribute__((ext_vector_type(8)));
typedef float f32x4 __attribute__((ext_vector_type(4)));
typedef unsigned short u16x4 __attribute__((ext_vector_type(4)));

#define KOFF 27

__device__ __forceinline__ float bf2f(u16 u) {
    u32 x = ((u32)u) << 16;
    return __builtin_bit_cast(float, x);
}
__device__ __forceinline__ u16 f2bf(float f) {
    u32 u = __builtin_bit_cast(u32, f);
    u32 r = (u + 0x7FFFu + ((u >> 16) & 1u)) >> 16;  // RNE
    return (u16)r;
}
__device__ __forceinline__ void async16(void* lds, const void* g) {
    __builtin_amdgcn_global_load_lds(
        (const __attribute__((address_space(1))) u32*)g,
        (__attribute__((address_space(3))) u32*)lds, 16, 0, 0);
}

// ---------------------------------------------------------------------------
// Fused weight prep (all 10 conv weights in one launch):
// W[k][c][d] fp32 -> bf16 Wt[k][d][c ^ ((d&7)<<3)]  (transpose + XOR swizzle
// baked in so conv's B-tile stages linearly via global_load_lds).
// grid = 10 weights * 27 k * 2 d-halves = 540 blocks.
// ---------------------------------------------------------------------------
struct WP {
    const float* s[10];
    u16* d[10];
};
__global__ __launch_bounds__(256) void prep_all(WP wp) {
    __shared__ float t[128][65];  // [c][dl], padded
    const int w = blockIdx.x / 54, bb = blockIdx.x % 54;
    const int k = bb >> 1, half = bb & 1;
    const float* s = wp.s[w] + k * 16384 + half * 64;
    for (int i = threadIdx.x; i < 8192; i += 256) {
        int c = i >> 6, dl = i & 63;
        t[c][dl] = s[c * 128 + dl];
    }
    __syncthreads();
    u16* db = wp.d[w] + k * 16384;
    for (int i = threadIdx.x; i < 8192; i += 256) {
        int dl = i >> 7, c = i & 127;
        int d = half * 64 + dl;
        db[d * 128 + (c ^ ((d & 7) << 3))] = f2bf(t[c][dl]);
    }
}

// f0[n][c] = prior_emb[x_O[n]][c]  (fp32 -> bf16)
__global__ __launch_bounds__(256) void embed_k(const int* __restrict__ xO,
                                               const float* __restrict__ emb,
                                               u16* __restrict__ out) {
    int idx = blockIdx.x * 256 + threadIdx.x;
    int c = idx & 127, n = idx >> 7;
    out[idx] = f2bf(emb[xO[n] * 128 + c]);
}

// g[m][c] = f[m>>3][c] + oct_emb[child_oct[m]][c]
__global__ __launch_bounds__(256) void expand_k(const u16* __restrict__ f,
                                                const int* __restrict__ oct,
                                                const float* __restrict__ oemb,
                                                u16* __restrict__ g) {
    int idx = blockIdx.x * 256 + threadIdx.x;
    int c = idx & 127, m = idx >> 7;
    g[idx] = f2bf(bf2f(f[(m >> 3) * 128 + c]) + oemb[oct[m] * 128 + c]);
}

// ---------------------------------------------------------------------------
// Pipelined sparse conv, BM=128 points/block, 512 threads (8 waves, 2/SIMD).
// Double-buffered A (gathered) + B (pre-swizzled weights) in LDS; counted
// s_waitcnt vmcnt(8) so next offset's 8 loads stay in flight across barriers.
// PARTIAL: split-K over offsets (blockIdx.y = group), writes fp32 partials.
// Swizzle: byte-in-row ^= (row&7)<<4 on both the staged source and the read.
// ---------------------------------------------------------------------------
template <bool PARTIAL>
__global__ __launch_bounds__(512, 1) void conv_pipe(
    const u16* __restrict__ fin, const int* __restrict__ nbr,
    const u16* __restrict__ wt, const u16* __restrict__ res,
    u16* __restrict__ fout, float* __restrict__ pout, int splits, int npts) {
    __shared__ __align__(16) u16 Asb[2][128 * 128];
    __shared__ __align__(16) u16 Bsb[2][128 * 128];
    __shared__ int nbrS[128 * KOFF];
    const int tid = threadIdx.x;
    const int wid = tid >> 6;
    const int lane = tid & 63;
    const int p0 = blockIdx.x * 128;
    const int g = blockIdx.y;
    const int k0 = (g * KOFF) / splits;
    const int k1 = ((g + 1) * KOFF) / splits;

    // cache this block's neighbor slice in LDS (keeps vmcnt counting exact)
    for (int i = tid; i < 128 * KOFF; i += 512)
        nbrS[i] = nbr[(p0 + i / KOFF) * KOFF + (i % KOFF)];
    __syncthreads();  // full drain: vmcnt==0 past this point

    f32x4 acc[2][4];
#pragma unroll
    for (int m = 0; m < 2; ++m)
#pragma unroll
        for (int n = 0; n < 4; ++n) acc[m][n] = f32x4{0.f, 0.f, 0.f, 0.f};

    const int RB = (wid >> 1) * 32;  // wave row base (4 row groups)
    const int CB = (wid & 1) * 64;   // wave col base (2 col groups)
    const int lrow = lane & 15;
    const int lkb = (lane >> 4) * 16;

    auto stage = [&](int k, int buf) {
        // A: gathered rows, swizzled per-lane global source, linear LDS dest
#pragma unroll
        for (int i = 0; i < 4; ++i) {
            int o = i * 8192 + tid * 16;
            int r = o >> 8;
            int cbs = (o & 255) ^ ((r & 7) << 4);
            int rg = nbrS[r * KOFF + k];
            async16((char*)&Asb[buf][0] + i * 8192 + wid * 1024,
                    (const char*)fin + rg * 256 + cbs);
        }
        // B: pre-swizzled weights, linear copy
        const char* wk = (const char*)wt + k * 32768;
#pragma unroll
        for (int i = 0; i < 4; ++i)
            async16((char*)&Bsb[buf][0] + i * 8192 + wid * 1024,
                    wk + i * 8192 + tid * 16);
    };

    stage(k0, 0);
    int cur = 0;
#pragma unroll 1
    for (int k = k0; k < k1; ++k) {
        if (k + 1 < k1) {
            stage(k + 1, cur ^ 1);  // outstanding: 16
            asm volatile("s_waitcnt vmcnt(8)" ::: "memory");  // cur's 8 done
        } else {
            asm volatile("s_waitcnt vmcnt(0)" ::: "memory");
        }
        __builtin_amdgcn_s_barrier();       // all waves' cur loads done
        __builtin_amdgcn_sched_barrier(0);  // fence: no ds_read hoisting
#pragma unroll
        for (int kk = 0; kk < 4; ++kk) {
            bf16x8 av[2], bv[4];
#pragma unroll
            for (int m = 0; m < 2; ++m) {
                int row = RB + m * 16 + lrow;
                int cb = (kk * 64 + lkb) ^ ((row & 7) << 4);
                av[m] = *(const bf16x8*)((const char*)&Asb[cur][0] + row * 256 + cb);
            }
#pragma unroll
            for (int n = 0; n < 4; ++n) {
                int drow = CB + n * 16 + lrow;
                int cb = (kk * 64 + lkb) ^ ((drow & 7) << 4);
                bv[n] = *(const bf16x8*)((const char*)&Bsb[cur][0] + drow * 256 + cb);
            }
#pragma unroll
            for (int m = 0; m < 2; ++m)
#pragma unroll
                for (int n = 0; n < 4; ++n)
                    acc[m][n] = __builtin_amdgcn_mfma_f32_16x16x32_bf16(
                        av[m], bv[n], acc[m][n], 0, 0, 0);
        }
        __builtin_amdgcn_s_barrier();  // all waves done reading cur
        cur ^= 1;
    }

    // epilogue.  D layout: col=lane&15, row=(lane>>4)*4+q
    if constexpr (PARTIAL) {
        float* pg = pout + (size_t)g * npts * 128;
#pragma unroll
        for (int m = 0; m < 2; ++m) {
            int prow = p0 + RB + m * 16 + (lane >> 4) * 4;
#pragma unroll
            for (int n = 0; n < 4; ++n) {
                int dcol = CB + n * 16 + lrow;
#pragma unroll
                for (int q = 0; q < 4; ++q)
                    pg[(prow + q) * 128 + dcol] = acc[m][n][q];
            }
        }
    } else {
#pragma unroll
        for (int m = 0; m < 2; ++m) {
            int prow = p0 + RB + m * 16 + (lane >> 4) * 4;
#pragma unroll
            for (int n = 0; n < 4; ++n) {
                int dcol = CB + n * 16 + lrow;
#pragma unroll
                for (int q = 0; q < 4; ++q) {
                    float v = acc[m][n][q];
                    int p = prow + q;
                    if (res) v += bf2f(res[p * 128 + dcol]);
                    v = v > 0.f ? v : 0.f;
                    fout[p * 128 + dcol] = f2bf(v);
                }
            }
        }
    }
}

// combine split-K partials: out = relu(sum_g P[g] (+ res)) -> bf16
// one thread = 4 consecutive channels; grid = npts*128/(256*4)
__global__ __launch_bounds__(256) void combine_k(const float* __restrict__ P,
                                                 const u16* __restrict__ res,
                                                 u16* __restrict__ fout,
                                                 int nelem) {
    int base = (blockIdx.x * 256 + threadIdx.x) * 4;
    f32x4 s = *(const f32x4*)(P + base);
#pragma unroll
    for (int gg = 1; gg < 8; ++gg)
        s += *(const f32x4*)(P + (size_t)gg * nelem + base);
    u16x4 o;
    if (res) {
        u16x4 rv = *(const u16x4*)(res + base);
#pragma unroll
        for (int j = 0; j < 4; ++j) s[j] += bf2f(rv[j]);
    }
#pragma unroll
    for (int j = 0; j < 4; ++j) {
        float v = s[j] > 0.f ? s[j] : 0.f;
        o[j] = f2bf(v);
    }
    *(u16x4*)(fout + base) = o;
}

// ---------------------------------------------------------------------------
// Heads: 8 points/block, both 2-layer MLP heads + softmax(16) + gathered
// -log2 prob, deterministic per-block partial sum.
// ---------------------------------------------------------------------------
__global__ __launch_bounds__(128) void heads_k(
    const u16* __restrict__ g, const int* __restrict__ gtO,
    const float* __restrict__ s1emb, const float* __restrict__ W1a,
    const float* __restrict__ b1a, const float* __restrict__ W2a,
    const float* __restrict__ b2a, const float* __restrict__ W1b,
    const float* __restrict__ b1b, const float* __restrict__ W2b,
    const float* __restrict__ b2b, float* __restrict__ partial) {
    __shared__ float gl[8][128];
    __shared__ float hl[8][128];
    __shared__ int gts[2][8];
    __shared__ float bitsv[16];
    const int tid = threadIdx.x;
    const int p0 = blockIdx.x * 8;
    if (tid < 8) {
        int gt = gtO[p0 + tid];
        gts[0][tid] = gt & 15;
        gts[1][tid] = gt >> 4;
    }
    for (int i = tid; i < 1024; i += 128)
        gl[i >> 7][i & 127] = bf2f(g[p0 * 128 + i]);
    __syncthreads();

    const int pp = tid >> 4, jj = tid & 15;
#pragma unroll
    for (int stage = 0; stage < 2; ++stage) {
        const float* W1 = stage ? W1b : W1a;
        const float* b1 = stage ? b1b : b1a;
        const float* W2 = stage ? W2b : W2a;
        const float* b2 = stage ? b2b : b2a;
        if (stage) {
#pragma unroll
            for (int p = 0; p < 8; ++p)
                gl[p][tid] += s1emb[gts[0][p] * 128 + tid];
            __syncthreads();
        }
        float a[8];
#pragma unroll
        for (int p = 0; p < 8; ++p) a[p] = b1[tid];
        for (int c = 0; c < 128; ++c) {
            float w = W1[c * 128 + tid];
#pragma unroll
            for (int p = 0; p < 8; ++p) a[p] = fmaf(gl[p][c], w, a[p]);
        }
        __syncthreads();
#pragma unroll
        for (int p = 0; p < 8; ++p) hl[p][tid] = a[p] > 0.f ? a[p] : 0.f;
        __syncthreads();
        float lg = b2[jj];
        for (int d = 0; d < 128; ++d) lg = fmaf(hl[pp][d], W2[d * 16 + jj], lg);
        float mx = lg;
#pragma unroll
        for (int o = 1; o < 16; o <<= 1) mx = fmaxf(mx, __shfl_xor(mx, o, 16));
        float e = expf(lg - mx);
        float sm = e;
#pragma unroll
        for (int o = 1; o < 16; o <<= 1) sm += __shfl_xor(sm, o, 16);
        if (jj == gts[stage][pp]) {
            float b = e / sm + 1e-10f;
            float bits = -log2f(b);
            bitsv[stage * 8 + pp] = fminf(fmaxf(bits, 0.f), 50.f);
        }
        __syncthreads();
    }
    if (tid == 0) {
        float s = 0.f;
#pragma unroll
        for (int i = 0; i < 16; ++i) s += bitsv[i];
        partial[blockIdx.x] = s;
    }
}

__global__ __launch_bounds__(256) void finalize_k(const float* __restrict__ partial,
                                                  float* __restrict__ out) {
    float s = 0.f;
    for (int i = threadIdx.x; i < 4096; i += 256) s += partial[i];
#pragma unroll
    for (int o = 32; o > 0; o >>= 1) s += __shfl_down(s, o, 64);
    __shared__ float wsum[4];
    if ((threadIdx.x & 63) == 0) wsum[threadIdx.x >> 6] = s;
    __syncthreads();
    if (threadIdx.x == 0)
        out[0] = (wsum[0] + wsum[1] + wsum[2] + wsum[3]) * (1.0f / 4096.0f);
}

// ---------------------------------------------------------------------------
extern "C" void kernel_launch(void* const* d_in, const int* in_sizes, int n_in,
                              void* d_out, int out_size, void* d_ws,
                              size_t ws_size, hipStream_t stream) {
    const int N = 4096, M = 32768;
    const int* x_O = (const int*)d_in[0];
    const int* gt_O = (const int*)d_in[1];
    const int* nbr_par = (const int*)d_in[2];
    const int* nbr_ch = (const int*)d_in[3];
    const int* child_oct = (const int*)d_in[4];
    const float* prior_emb = (const float*)d_in[5];
    const float* convW[10] = {
        (const float*)d_in[6],  (const float*)d_in[7],  (const float*)d_in[8],
        (const float*)d_in[9],  (const float*)d_in[10], (const float*)d_in[12],
        (const float*)d_in[13], (const float*)d_in[14], (const float*)d_in[15],
        (const float*)d_in[16]};
    const float* oct_emb = (const float*)d_in[11];
    const float* s1_emb = (const float*)d_in[17];
    const float* h0W1 = (const float*)d_in[18];
    const float* h0b1 = (const float*)d_in[19];
    const float* h0W2 = (const float*)d_in[20];
    const float* h0b2 = (const float*)d_in[21];
    const float* h1W1 = (const float*)d_in[22];
    const float* h1b1 = (const float*)d_in[23];
    const float* h1W2 = (const float*)d_in[24];
    const float* h1b2 = (const float*)d_in[25];

    // workspace layout (~37 MB)
    char* ws = (char*)d_ws;
    size_t off = 0;
    auto alloc = [&](size_t b) {
        void* p = ws + off;
        off += (b + 255) & ~(size_t)255;
        return p;
    };
    WP wp;
    for (int i = 0; i < 10; ++i) {
        wp.s[i] = convW[i];
        wp.d[i] = (u16*)alloc(27 * 128 * 128 * 2);
    }
    u16* fA = (u16*)alloc((size_t)N * 256);
    u16* fB = (u16*)alloc((size_t)N * 256);
    u16* fC = (u16*)alloc((size_t)N * 256);
    u16* gA = (u16*)alloc((size_t)M * 256);
    u16* gB = (u16*)alloc((size_t)M * 256);
    u16* gC = (u16*)alloc((size_t)M * 256);
    float* partial = (float*)alloc(4096 * 4);
    // split-K parent partials (8 * N * 128 fp32 = 16 MB) alias the child
    // feature region: dead before expand_k writes gA.
    float* pconv = (float*)gA;

    prep_all<<<540, 256, 0, stream>>>(wp);
    embed_k<<<N * 128 / 256, 256, 0, stream>>>(x_O, prior_emb, fA);

    const int PE = N * 128;  // partial stride (elements)
    // parent stack (split-K, grid 32x8)
    conv_pipe<true><<<dim3(32, 8), 512, 0, stream>>>(fA, nbr_par, wp.d[0], nullptr, nullptr, pconv, 8, N);
    combine_k<<<PE / 1024, 256, 0, stream>>>(pconv, nullptr, fB, PE);
    conv_pipe<true><<<dim3(32, 8), 512, 0, stream>>>(fB, nbr_par, wp.d[1], nullptr, nullptr, pconv, 8, N);
    combine_k<<<PE / 1024, 256, 0, stream>>>(pconv, nullptr, fC, PE);
    conv_pipe<true><<<dim3(32, 8), 512, 0, stream>>>(fC, nbr_par, wp.d[2], nullptr, nullptr, pconv, 8, N);
    combine_k<<<PE / 1024, 256, 0, stream>>>(pconv, fB, fA, PE);
    conv_pipe<true><<<dim3(32, 8), 512, 0, stream>>>(fA, nbr_par, wp.d[3], nullptr, nullptr, pconv, 8, N);
    combine_k<<<PE / 1024, 256, 0, stream>>>(pconv, nullptr, fC, PE);
    conv_pipe<true><<<dim3(32, 8), 512, 0, stream>>>(fC, nbr_par, wp.d[4], nullptr, nullptr, pconv, 8, N);
    combine_k<<<PE / 1024, 256, 0, stream>>>(pconv, fA, fB, PE);

    // expand to children
    expand_k<<<M * 128 / 256, 256, 0, stream>>>(fB, child_oct, oct_emb, gA);

    // child stack (full-K pipelined, grid 256)
    conv_pipe<false><<<dim3(256, 1), 512, 0, stream>>>(gA, nbr_ch, wp.d[5], nullptr, gB, nullptr, 1, M);
    conv_pipe<false><<<dim3(256, 1), 512, 0, stream>>>(gB, nbr_ch, wp.d[6], nullptr, gC, nullptr, 1, M);
    conv_pipe<false><<<dim3(256, 1), 512, 0, stream>>>(gC, nbr_ch, wp.d[7], gB, gA, nullptr, 1, M);
    conv_pipe<false><<<dim3(256, 1), 512, 0, stream>>>(gA, nbr_ch, wp.d[8], nullptr, gC, nullptr, 1, M);
    conv_pipe<false><<<dim3(256, 1), 512, 0, stream>>>(gC, nbr_ch, wp.d[9], gA, gB, nullptr, 1, M);

    heads_k<<<M / 8, 128, 0, stream>>>(gB, gt_O, s1_emb, h0W1, h0b1, h0W2, h0b2,
                                       h1W1, h1b1, h1W2, h1b2, partial);
    finalize_k<<<1, 256, 0, stream>>>(partial, (float*)d_out);

    (void)in_sizes; (void)n_in; (void)out_size; (void)ws_size;
}